// Round 5
// baseline (1258.543 us; speedup 1.0000x reference)
//
#include <hip/hip_runtime.h>
#include <hip/hip_bf16.h>
#include <math.h>

typedef __hip_bfloat16 bf16;
typedef __attribute__((ext_vector_type(8))) short bf16x8;   // 8 bf16 = 4 VGPRs (MFMA A/B frag)
typedef __attribute__((ext_vector_type(4))) float f32x4;    // MFMA C/D frag

__device__ __forceinline__ void glds16(const bf16* g, bf16* l) {
    __builtin_amdgcn_global_load_lds(
        (const __attribute__((address_space(1))) void*)g,
        (__attribute__((address_space(3))) void*)l, 16, 0, 0);
}

// ---------------------------------------------------------------------------
// Self-detecting convert: each wave inspects the tensor's first 128 ushorts.
// True bf16 N(0,1): no exponent >= 0x86 (|x|>=128). fp32 reinterpreted: even
// ushorts are low-mantissa halves, ~47% have exp>=0x86. Wave-uniform branch.
// (Empirically: inputs ARE fp32 — round1 NaN -> round2 finite proved it.)
// ---------------------------------------------------------------------------
__global__ __launch_bounds__(256)
void convert_to_bf16(const void* __restrict__ src, bf16* __restrict__ dst, long n) {
    const unsigned short* u16 = (const unsigned short*)src;
    int lane = threadIdx.x & 63;
    unsigned short u = u16[lane * 2];
    int e = (u >> 7) & 0xFF;
    int isf32 = __popcll(__ballot(e >= 0x86)) > 4;   // wave-uniform
    long i = ((long)blockIdx.x * 256 + threadIdx.x) * 8;
    if (i >= n) return;
    if (isf32) {
        const float* s = (const float*)src;
        bf16x8 o;
        #pragma unroll
        for (int j = 0; j < 8; j++) {
            bf16 b = (bf16)s[i + j];
            o[j] = *(short*)&b;
        }
        *(bf16x8*)(dst + i) = o;
    } else {
        *(bf16x8*)(dst + i) = *(const bf16x8*)((const bf16*)src + i);
    }
}

// ---------------------------------------------------------------------------
// GEMM: C[M][N] = clip?(A[M][K] @ B[N][K]^T). bf16 in, fp32 accum, OUT out.
// m97 structure: 128x128 tile, BK=32, global_load_lds width=16, 4 waves 2x2.
// OUT=bf16 for intermediates, OUT=float for the final output (d_out is fp32!).
// ---------------------------------------------------------------------------
template<bool CLIP, typename OUT>
__global__ __launch_bounds__(256)
void gemm_bt(const bf16* __restrict__ A, const bf16* __restrict__ B,
             OUT* __restrict__ C, int M, int N, int K) {
    __shared__ __align__(16) bf16 sA[128 * 32];
    __shared__ __align__(16) bf16 sB[128 * 32];
    const int tid  = threadIdx.x;
    const int lane = tid & 63;
    const int wave = tid >> 6;
    const int wm   = wave >> 1;
    const int wn   = wave & 1;
    const int row  = lane & 15;
    const int quad = lane >> 4;
    const int bn = blockIdx.x, bm = blockIdx.y;

    const int r  = tid >> 2;            // 0..63
    const int kc = (tid & 3) * 8;       // 0,8,16,24
    const bf16* gA = A + (size_t)(bm * 128 + r) * K + kc;
    const bf16* gB = B + (size_t)(bn * 128 + r) * K + kc;
    bf16* lA = sA + tid * 8;            // contiguous in tid => glds-compatible
    bf16* lB = sB + tid * 8;

    f32x4 acc[4][4] = {};

    for (int kt = 0; kt < K; kt += 32) {
        glds16(gA + kt,                    lA);
        glds16(gA + kt + (size_t)64 * K,   lA + 2048);
        glds16(gB + kt,                    lB);
        glds16(gB + kt + (size_t)64 * K,   lB + 2048);
        __syncthreads();
        bf16x8 af[4], bfr[4];
        #pragma unroll
        for (int mt = 0; mt < 4; mt++)
            af[mt] = *(const bf16x8*)(sA + (wm * 64 + mt * 16 + row) * 32 + quad * 8);
        #pragma unroll
        for (int nt = 0; nt < 4; nt++)
            bfr[nt] = *(const bf16x8*)(sB + (wn * 64 + nt * 16 + row) * 32 + quad * 8);
        #pragma unroll
        for (int mt = 0; mt < 4; mt++)
            #pragma unroll
            for (int nt = 0; nt < 4; nt++)
                acc[mt][nt] = __builtin_amdgcn_mfma_f32_16x16x32_bf16(
                    af[mt], bfr[nt], acc[mt][nt], 0, 0, 0);
        __syncthreads();
    }

    #pragma unroll
    for (int mt = 0; mt < 4; mt++) {
        #pragma unroll
        for (int nt = 0; nt < 4; nt++) {
            #pragma unroll
            for (int v = 0; v < 4; v++) {
                float val = acc[mt][nt][v];
                if (CLIP) val = fminf(fmaxf(val, -8.0f), 8.0f);
                // C/D layout: col = lane&15, row = quad*4 + v  [m89/m91]
                int grow = bm * 128 + wm * 64 + mt * 16 + quad * 4 + v;
                int gcol = bn * 128 + wn * 64 + nt * 16 + row;
                C[(size_t)grow * N + gcol] = (OUT)val;
            }
        }
    }
}

// ---------------------------------------------------------------------------
// RoPE + reorder: qkv[token][6144] -> Q[b][32][l][128] (roped),
// K[b][8][l][128] (roped), VT[b][8][128][l] (transposed copy).
// ---------------------------------------------------------------------------
__global__ __launch_bounds__(256)
void rope_reorder(const bf16* __restrict__ qkv, bf16* __restrict__ Q,
                  bf16* __restrict__ Kd, bf16* __restrict__ VT) {
    const int token = blockIdx.y;                          // 0..4095
    const int slot  = blockIdx.x * 4 + (threadIdx.x >> 6); // 0..47
    const int lane  = threadIdx.x & 63;
    const int b = token >> 11, l = token & 2047;
    const bf16* src = qkv + (size_t)token * 6144 + slot * 128;
    if (slot < 40) {
        float x1 = __bfloat162float(src[lane]);
        float x2 = __bfloat162float(src[lane + 64]);
        float inv_freq = powf(500000.0f, -(float)lane * (1.0f / 64.0f));
        float ang = (float)l * inv_freq;
        float s, c;
        sincosf(ang, &s, &c);
        float o1 = x1 * c - x2 * s;
        float o2 = x2 * c + x1 * s;
        bf16* dst;
        if (slot < 32) dst = Q  + ((size_t)(b * 32 + slot)        * 2048 + l) * 128;
        else           dst = Kd + ((size_t)(b * 8  + (slot - 32)) * 2048 + l) * 128;
        dst[lane]      = (bf16)o1;
        dst[lane + 64] = (bf16)o2;
    } else {
        bf16* dst = VT + (size_t)(b * 8 + (slot - 40)) * 128 * 2048 + l;
        dst[(size_t)lane * 2048]        = src[lane];
        dst[(size_t)(lane + 64) * 2048] = src[lane + 64];
    }
}

// ---------------------------------------------------------------------------
// Flash attention, causal, GQA 4:1. Q-tile 64, K-tile 64, 4 waves (16 q rows
// each). Plain row-major LDS with padded strides (136/72 elems, 16B-aligned).
// ---------------------------------------------------------------------------
#define SQ_STR 136
#define SV_STR 72
#define SP_STR 72

__global__ __launch_bounds__(256)
void attn_kernel(const bf16* __restrict__ Q, const bf16* __restrict__ K,
                 const bf16* __restrict__ V, bf16* __restrict__ Oout) {
    const int qt = blockIdx.x;          // 0..31 (q-tile of 64 rows)
    const int bh = blockIdx.y;          // 0..63
    const int b = bh >> 5, h = bh & 31;
    const int kh = h >> 2;              // GQA: head h uses kv-head h/4
    const bf16* Qp = Q + ((size_t)(b * 32 + h) * 2048 + qt * 64) * 128;
    const bf16* Kp = K + (size_t)(b * 8 + kh) * 2048 * 128;
    const bf16* Vp = V + (size_t)(b * 8 + kh) * 128 * 2048;   // [d][l]

    __shared__ __align__(16) bf16 sQ[64 * SQ_STR];
    __shared__ __align__(16) bf16 sK[64 * SQ_STR];
    __shared__ __align__(16) bf16 sV[128 * SV_STR];
    __shared__ __align__(16) bf16 sP[4 * 16 * SP_STR];

    const int tid = threadIdx.x, lane = tid & 63, wave = tid >> 6;
    const int row = lane & 15, quad = lane >> 4;

    for (int u = tid; u < 1024; u += 256) {
        int r = u >> 4, g = u & 15;
        *(bf16x8*)(sQ + r * SQ_STR + g * 8) = *(const bf16x8*)(Qp + r * 128 + g * 8);
    }

    float pm[4], pl[4];
    f32x4 o_acc[8] = {};
    #pragma unroll
    for (int v = 0; v < 4; v++) { pm[v] = -1e30f; pl[v] = 0.0f; }
    const float scale = 0.08838834764831845f;   // 1/sqrt(128)

    for (int jj = 0; jj <= qt; jj++) {
        __syncthreads();   // prior iter's LDS reads done; also covers Q stage
        for (int u = tid; u < 1024; u += 256) {
            int r = u >> 4, g = u & 15;
            *(bf16x8*)(sK + r * SQ_STR + g * 8) =
                *(const bf16x8*)(Kp + (size_t)jj * 8192 + r * 128 + g * 8);
        }
        for (int u = tid; u < 1024; u += 256) {
            int r = u >> 3, g = u & 7;   // r = d (0..127), g over 64 kpos
            *(bf16x8*)(sV + r * SV_STR + g * 8) =
                *(const bf16x8*)(Vp + (size_t)r * 2048 + jj * 64 + g * 8);
        }
        __syncthreads();

        // S = Q K^T. A-frag: A[m=lane&15][k=quad*8+j]; wave owns 16 q rows.
        bf16x8 aq[4];
        #pragma unroll
        for (int kk = 0; kk < 4; kk++)
            aq[kk] = *(const bf16x8*)(sQ + (wave * 16 + row) * SQ_STR + (kk * 4 + quad) * 8);
        f32x4 s_acc[4] = {};
        #pragma unroll
        for (int nt = 0; nt < 4; nt++) {
            #pragma unroll
            for (int kk = 0; kk < 4; kk++) {
                bf16x8 bk = *(const bf16x8*)(sK + (nt * 16 + row) * SQ_STR + (kk * 4 + quad) * 8);
                s_acc[nt] = __builtin_amdgcn_mfma_f32_16x16x32_bf16(
                    aq[kk], bk, s_acc[nt], 0, 0, 0);
            }
        }
        // scale + causal mask (diagonal tile only)
        #pragma unroll
        for (int nt = 0; nt < 4; nt++) {
            #pragma unroll
            for (int v = 0; v < 4; v++) {
                float s = s_acc[nt][v] * scale;
                if (jj == qt) {
                    int kpos = nt * 16 + row;
                    int qrow = wave * 16 + quad * 4 + v;
                    if (kpos > qrow) s = -1e30f;
                }
                s_acc[nt][v] = s;
            }
        }
        // online softmax
        float mx[4];
        #pragma unroll
        for (int v = 0; v < 4; v++)
            mx[v] = fmaxf(fmaxf(s_acc[0][v], s_acc[1][v]),
                          fmaxf(s_acc[2][v], s_acc[3][v]));
        #pragma unroll
        for (int off = 1; off < 16; off <<= 1)
            #pragma unroll
            for (int v = 0; v < 4; v++)
                mx[v] = fmaxf(mx[v], __shfl_xor(mx[v], off, 64));
        float mn[4], al[4], rs[4] = {0, 0, 0, 0};
        #pragma unroll
        for (int v = 0; v < 4; v++) {
            mn[v] = fmaxf(pm[v], mx[v]);
            al[v] = __expf(pm[v] - mn[v]);
            pm[v] = mn[v];
        }
        // P = exp(S-m): C-layout -> A-layout via LDS
        #pragma unroll
        for (int nt = 0; nt < 4; nt++) {
            #pragma unroll
            for (int v = 0; v < 4; v++) {
                float p = __expf(s_acc[nt][v] - mn[v]);
                rs[v] += p;
                int rr = quad * 4 + v;
                int c  = nt * 16 + row;
                sP[(wave * 16 + rr) * SP_STR + c] = (bf16)p;
            }
        }
        #pragma unroll
        for (int off = 1; off < 16; off <<= 1)
            #pragma unroll
            for (int v = 0; v < 4; v++)
                rs[v] += __shfl_xor(rs[v], off, 64);
        #pragma unroll
        for (int v = 0; v < 4; v++) pl[v] = pl[v] * al[v] + rs[v];
        #pragma unroll
        for (int dt = 0; dt < 8; dt++)
            #pragma unroll
            for (int v = 0; v < 4; v++) o_acc[dt][v] *= al[v];
        __syncthreads();   // sP visible

        // O += P V
        #pragma unroll
        for (int kk = 0; kk < 2; kk++) {
            bf16x8 pa = *(const bf16x8*)(sP + (wave * 16 + row) * SP_STR + (kk * 4 + quad) * 8);
            #pragma unroll
            for (int dt = 0; dt < 8; dt++) {
                bf16x8 vb = *(const bf16x8*)(sV + (dt * 16 + row) * SV_STR + (kk * 4 + quad) * 8);
                o_acc[dt] = __builtin_amdgcn_mfma_f32_16x16x32_bf16(
                    pa, vb, o_acc[dt], 0, 0, 0);
            }
        }
    }

    // epilogue: O / l, write token-major [token][h*128+d]
    const int token = b * 2048 + qt * 64 + wave * 16;
    #pragma unroll
    for (int dt = 0; dt < 8; dt++) {
        #pragma unroll
        for (int v = 0; v < 4; v++) {
            float o = o_acc[dt][v] / pl[v];
            int trow = token + quad * 4 + v;
            Oout[(size_t)trow * 4096 + h * 128 + dt * 16 + row] = (bf16)o;
        }
    }
}

// ---------------------------------------------------------------------------
// Workspace plan (peak 128 MB; all regions fully rewritten each call):
//   0..32   xb (x as bf16)   -> later overwritten by attn output
//   32..80  Wqkvb            -> after GEMM1: Qb(32..64) Kb(64..72) VTb(72..80)
//   80..128 qkv              -> after rope:  Woutb(80..112)
// d_out is FLOAT32 (reference output dtype) — 64 MB.
// ---------------------------------------------------------------------------
extern "C" void kernel_launch(void* const* d_in, const int* in_sizes, int n_in,
                              void* d_out, int out_size, void* d_ws, size_t ws_size,
                              hipStream_t stream) {
    float* out = (float*)d_out;                // (2,2048,4096) float32

    const size_t MB = 1024 * 1024;
    char* ws = (char*)d_ws;
    bf16* xb    = (bf16*)(ws);                 // 0..32 MB
    bf16* Wqkvb = (bf16*)(ws + 32 * MB);       // 32..80 MB
    bf16* qkv   = (bf16*)(ws + 80 * MB);       // 80..128 MB
    bf16* Qb    = (bf16*)(ws + 32 * MB);       // over dead Wqkvb
    bf16* Kb    = (bf16*)(ws + 64 * MB);
    bf16* VTb   = (bf16*)(ws + 72 * MB);
    bf16* Woutb = (bf16*)(ws + 80 * MB);       // over dead qkv
    bf16* attn  = xb;                          // over dead xb

    convert_to_bf16<<<8192,  256, 0, stream>>>(d_in[0], xb,    16777216L);
    convert_to_bf16<<<12288, 256, 0, stream>>>(d_in[1], Wqkvb, 25165824L);
    // 1) qkv = clip(x @ Wqkv^T, +-8)   (bf16 out)
    gemm_bt<true, bf16><<<dim3(48, 32), 256, 0, stream>>>(xb, Wqkvb, qkv, 4096, 6144, 4096);
    // 2) rope + reorder (reads 80..128, writes 32..80)
    rope_reorder<<<dim3(12, 4096), 256, 0, stream>>>(qkv, Qb, Kb, VTb);
    // (qkv now dead; stage Wout there)
    convert_to_bf16<<<8192,  256, 0, stream>>>(d_in[2], Woutb, 16777216L);
    // 3) causal GQA flash attention -> attn[token][4096] (reads 32..80, writes 0..32)
    attn_kernel<<<dim3(32, 64), 256, 0, stream>>>(Qb, Kb, VTb, attn);
    // 4) out = attn @ Wout^T            (FLOAT out -> d_out)
    gemm_bt<false, float><<<dim3(32, 32), 256, 0, stream>>>(attn, Woutb, out, 4096, 4096, 4096);
}